// Round 1
// baseline (2021.235 us; speedup 1.0000x reference)
//
#include <hip/hip_runtime.h>
#include <hip/hip_bf16.h>
#include <math.h>

#define BB 2
#define N_TOK 4280
#define WH 4096
#define NOBJ 30
#define QDIM 320
#define HEADS 8
#define DHEAD 40
#define INNER 320
#define M_ROWS (BB * N_TOK)   /* 8560 */

// -------------------- pack object masks into 30-bit words --------------------
__global__ void k_bits(const float* __restrict__ att, unsigned* __restrict__ bits) {
    int gid = blockIdx.x * blockDim.x + threadIdx.x;
    if (gid >= BB * WH) return;
    int b = gid / WH, i = gid % WH;
    unsigned v = 0;
    const float* base = att + (size_t)b * NOBJ * WH + i;
    #pragma unroll
    for (int o = 0; o < NOBJ; ++o)
        if (base[(size_t)o * WH] > 0.5f) v |= (1u << o);
    bits[gid] = v;
}

// ---------- GEMM: C[M,320] = A[M,320] @ W[320,320] (+ optional bias) ----------
template<bool BIAS>
__global__ __launch_bounds__(256) void k_gemm(const float* __restrict__ A,
                                              const float* __restrict__ W,
                                              const float* __restrict__ bias,
                                              float* __restrict__ C, int M) {
    __shared__ float As[16][68];   // [k][m], padded
    __shared__ float Ws[16][68];   // [k][n], padded
    const int tid = threadIdx.x;
    const int tx = tid & 15, ty = tid >> 4;
    const int m0 = blockIdx.x * 64, n0 = blockIdx.y * 64;
    float acc[4][4] = {};
    for (int k0 = 0; k0 < QDIM; k0 += 16) {
        #pragma unroll
        for (int idx = tid; idx < 64 * 16; idx += 256) {
            int m = idx >> 4, kk = idx & 15;
            float v = 0.f;
            if (m0 + m < M) v = A[(size_t)(m0 + m) * QDIM + k0 + kk];
            As[kk][m] = v;
        }
        #pragma unroll
        for (int idx = tid; idx < 16 * 64; idx += 256) {
            int kk = idx >> 6, n = idx & 63;
            Ws[kk][n] = W[(size_t)(k0 + kk) * QDIM + n0 + n];
        }
        __syncthreads();
        #pragma unroll
        for (int kk = 0; kk < 16; ++kk) {
            float4 a = *(const float4*)&As[kk][ty * 4];
            float4 w = *(const float4*)&Ws[kk][tx * 4];
            float av[4] = {a.x, a.y, a.z, a.w};
            float wv[4] = {w.x, w.y, w.z, w.w};
            #pragma unroll
            for (int ii = 0; ii < 4; ++ii)
                #pragma unroll
                for (int jj = 0; jj < 4; ++jj)
                    acc[ii][jj] += av[ii] * wv[jj];
        }
        __syncthreads();
    }
    #pragma unroll
    for (int ii = 0; ii < 4; ++ii) {
        int mm = m0 + ty * 4 + ii;
        if (mm >= M) continue;
        float4 v = make_float4(acc[ii][0], acc[ii][1], acc[ii][2], acc[ii][3]);
        if (BIAS) {
            float4 bv = *(const float4*)&bias[n0 + tx * 4];
            v.x += bv.x; v.y += bv.y; v.z += bv.z; v.w += bv.w;
        }
        *(float4*)&C[(size_t)mm * QDIM + n0 + tx * 4] = v;
    }
}

// ------------------------------ fused attention ------------------------------
#define RT 32
#define JT 64
__global__ __launch_bounds__(256) void k_attn(const float* __restrict__ Q,
                                              const float* __restrict__ K,
                                              const float* __restrict__ V,
                                              const unsigned* __restrict__ bits,
                                              float* __restrict__ O) {
    __shared__ float Ks[JT][DHEAD];
    __shared__ float Vs[JT][DHEAD];
    __shared__ float Ps[RT][JT + 1];
    __shared__ unsigned bJ[JT];

    const int tid = threadIdx.x;
    const int bh = blockIdx.y;
    const int b = bh >> 3, h = bh & 7;
    const int row0 = blockIdx.x * RT;
    const int r = tid >> 3;          // 0..31: my query row within block
    const int lane8 = tid & 7;       // 8 threads per row
    const int i = row0 + r;
    const bool rowvalid = (i < N_TOK);
    const int iq = rowvalid ? i : 0;
    const int d0 = lane8 * 5;
    const float LOG2E = 1.4426950408889634f;

    // q row in registers, pre-scaled
    float q[DHEAD];
    {
        const float scale = 0.15811388300841897f;  // 40^-0.5
        const float* qp = Q + ((size_t)(b * N_TOK + iq)) * INNER + h * DHEAD;
        #pragma unroll
        for (int d = 0; d < DHEAD; ++d) q[d] = qp[d] * scale;
    }
    const unsigned bitsI = (i < WH) ? bits[b * WH + i] : 0u;

    float m = -3.0e38f, l = 0.f;
    float acc[5] = {0.f, 0.f, 0.f, 0.f, 0.f};

    for (int j0 = 0; j0 < N_TOK; j0 += JT) {
        const int jc = min(JT, N_TOK - j0);
        __syncthreads();
        // stage K/V tile + key bits
        for (int idx = tid; idx < jc * DHEAD; idx += 256) {
            int jj = idx / DHEAD, d = idx % DHEAD;
            size_t g = ((size_t)(b * N_TOK + j0 + jj)) * INNER + h * DHEAD + d;
            Ks[jj][d] = K[g];
            Vs[jj][d] = V[g];
        }
        for (int idx = tid; idx < jc; idx += 256) {
            int j = j0 + idx;
            bJ[idx] = (j < WH) ? bits[b * WH + j] : 0u;
        }
        __syncthreads();

        // ---- S phase: 8 cols per thread (interleaved for LDS banks) ----
        float sv[8];
        float pmax = -3.0e38f;
        #pragma unroll
        for (int cc = 0; cc < 8; ++cc) {
            int c = lane8 + cc * 8;
            float s = -3.0e38f;
            if (c < jc && rowvalid) {
                int j = j0 + c;
                bool ok;
                if (i == j) ok = true;
                else if (i < WH) {
                    if (j < WH) ok = (bitsI & bJ[c]) != 0u;
                    else if (j < WH + 4 * NOBJ) {
                        int cI = j - WH;
                        int om = (cI < NOBJ) ? cI : (cI - 3 * NOBJ);
                        ok = ((unsigned)(cI - NOBJ) < (unsigned)(2 * NOBJ)) ||
                             (om >= 0 && ((bitsI >> om) & 1u));
                    } else ok = true;
                } else if (i < WH + 4 * NOBJ) {
                    if (j < WH) {
                        int rI = i - WH;
                        int om = (rI < NOBJ) ? rI : (rI - 3 * NOBJ);
                        ok = ((unsigned)(rI - NOBJ) < (unsigned)(2 * NOBJ)) ||
                             (om >= 0 && ((bJ[c] >> om) & 1u));
                    } else ok = true;
                } else ok = true;
                if (ok) {
                    float d0acc = 0.f;
                    #pragma unroll
                    for (int d4 = 0; d4 < DHEAD; d4 += 4) {
                        float4 kv = *(const float4*)&Ks[c][d4];
                        d0acc += q[d4] * kv.x + q[d4 + 1] * kv.y +
                                 q[d4 + 2] * kv.z + q[d4 + 3] * kv.w;
                    }
                    s = d0acc;
                }
            }
            sv[cc] = s;
            pmax = fmaxf(pmax, s);
        }
        #pragma unroll
        for (int off = 1; off < 8; off <<= 1)
            pmax = fmaxf(pmax, __shfl_xor(pmax, off, 64));

        float mnew = fmaxf(m, pmax);
        float rescale = __builtin_amdgcn_exp2f((m - mnew) * LOG2E);
        float psum = 0.f;
        #pragma unroll
        for (int cc = 0; cc < 8; ++cc) {
            int c = lane8 + cc * 8;
            float p = 0.f;
            if (sv[cc] > -1.0e38f)
                p = __builtin_amdgcn_exp2f((sv[cc] - mnew) * LOG2E);
            psum += p;
            Ps[r][c] = p;
        }
        #pragma unroll
        for (int off = 1; off < 8; off <<= 1)
            psum += __shfl_xor(psum, off, 64);
        m = mnew;
        l = l * rescale + psum;
        __syncthreads();

        // ---- PV phase: each thread owns (row r, dims d0..d0+4) ----
        #pragma unroll
        for (int t5 = 0; t5 < 5; ++t5) acc[t5] *= rescale;
        for (int jj = 0; jj < jc; ++jj) {
            float p = Ps[r][jj];
            #pragma unroll
            for (int t5 = 0; t5 < 5; ++t5)
                acc[t5] += p * Vs[jj][d0 + t5];
        }
    }

    if (rowvalid) {
        float inv = 1.0f / l;
        float* op = O + ((size_t)(b * N_TOK + i)) * INNER + h * DHEAD + d0;
        #pragma unroll
        for (int t5 = 0; t5 < 5; ++t5) op[t5] = acc[t5] * inv;
    }
}

// --------------------------------- launcher ----------------------------------
extern "C" void kernel_launch(void* const* d_in, const int* in_sizes, int n_in,
                              void* d_out, int out_size, void* d_ws, size_t ws_size,
                              hipStream_t stream) {
    const float* x   = (const float*)d_in[0];
    const float* att = (const float*)d_in[1];
    const float* Wq  = (const float*)d_in[2];
    const float* Wk  = (const float*)d_in[3];
    const float* Wv  = (const float*)d_in[4];
    const float* Wo  = (const float*)d_in[5];
    const float* bo  = (const float*)d_in[6];
    float* out = (float*)d_out;

    char* w = (char*)d_ws;
    unsigned* bits = (unsigned*)w;                       // 32 KB
    float* Qp = (float*)(w + 32768);
    float* Kp = Qp + (size_t)M_ROWS * QDIM;
    float* Vp = Kp + (size_t)M_ROWS * QDIM;
    float* AO = Vp + (size_t)M_ROWS * QDIM;

    k_bits<<<(BB * WH + 255) / 256, 256, 0, stream>>>(att, bits);

    dim3 gg((M_ROWS + 63) / 64, QDIM / 64);
    k_gemm<false><<<gg, 256, 0, stream>>>(x, Wq, nullptr, Qp, M_ROWS);
    k_gemm<false><<<gg, 256, 0, stream>>>(x, Wk, nullptr, Kp, M_ROWS);
    k_gemm<false><<<gg, 256, 0, stream>>>(x, Wv, nullptr, Vp, M_ROWS);

    dim3 ga((N_TOK + RT - 1) / RT, BB * HEADS);
    k_attn<<<ga, 256, 0, stream>>>(Qp, Kp, Vp, bits, AO);

    k_gemm<true><<<gg, 256, 0, stream>>>(AO, Wo, bo, out, M_ROWS);
}

// Round 2
// 474.827 us; speedup vs baseline: 4.2568x; 4.2568x over previous
//
#include <hip/hip_runtime.h>
#include <hip/hip_bf16.h>

#define BB 2
#define N_TOK 4280
#define NPAD 4288
#define WH 4096
#define NOBJ 30
#define QDIM 320
#define HEADS 8
#define DHEAD 40
#define INNER 320
#define M_ROWS (BB * N_TOK)   /* 8560 */
#define NEGF (-3.0e38f)

typedef __attribute__((ext_vector_type(8))) short short8;
typedef __attribute__((ext_vector_type(4))) short short4v;
typedef __attribute__((ext_vector_type(4))) float f32x4;
typedef __attribute__((ext_vector_type(4))) unsigned uintx4;
typedef __attribute__((ext_vector_type(2))) unsigned long long u64x2;

#define GLD16(lds, g) __builtin_amdgcn_global_load_lds( \
    (const __attribute__((address_space(1))) unsigned*)(g), \
    (__attribute__((address_space(3))) unsigned*)(lds), 16, 0, 0)
#define GLD4(lds, g) __builtin_amdgcn_global_load_lds( \
    (const __attribute__((address_space(1))) unsigned*)(g), \
    (__attribute__((address_space(3))) unsigned*)(lds), 4, 0, 0)

__device__ __forceinline__ ushort f2bf(float x) {
    union { __hip_bfloat16 h; ushort u; } cv;
    cv.h = __float2bfloat16(x);
    return cv.u;
}

// -------------------- zero the bf16 staging buffers --------------------
__global__ void k_zero(u64x2* __restrict__ p, int n16) {
    int stride = gridDim.x * blockDim.x;
    u64x2 z = {0ull, 0ull};
    for (int i = blockIdx.x * blockDim.x + threadIdx.x; i < n16; i += stride)
        p[i] = z;
}

// -------------------- pack object masks into 30-bit words (padded) -----
__global__ void k_bits(const float* __restrict__ att, unsigned* __restrict__ bits) {
    int gid = blockIdx.x * blockDim.x + threadIdx.x;
    if (gid >= BB * NPAD) return;
    int b = gid / NPAD, i = gid - b * NPAD;
    unsigned v = 0;
    if (i < WH) {
        const float* base = att + (size_t)b * NOBJ * WH + i;
        #pragma unroll
        for (int o = 0; o < NOBJ; ++o)
            if (base[(size_t)o * WH] > 0.5f) v |= (1u << o);
    }
    bits[gid] = v;
}

// ---------- GEMM: C[M,320] = A[M,320] @ W[320,320], mode-dependent epilogue
// MODE 0: f32 out + bias.  MODE 1: Qb bf16 [bh][tok][64] * (scale*log2e).
// MODE 2: Kb bf16 [bh][tok][64].  MODE 3: Vt bf16 [bh][48][NPAD] transposed.
template<int MODE>
__global__ __launch_bounds__(256) void k_gemm(const float* __restrict__ A,
                                              const float* __restrict__ W,
                                              const float* __restrict__ bias,
                                              void* __restrict__ dstv, int M) {
    __shared__ float As[16][68];
    __shared__ float Ws[16][68];
    const int tid = threadIdx.x;
    const int tx = tid & 15, ty = tid >> 4;
    const int m0 = blockIdx.x * 64, n0 = blockIdx.y * 64;
    float acc[4][4] = {};
    for (int k0 = 0; k0 < QDIM; k0 += 16) {
        #pragma unroll
        for (int idx = tid; idx < 64 * 16; idx += 256) {
            int m = idx >> 4, kk = idx & 15;
            float v = 0.f;
            if (m0 + m < M) v = A[(size_t)(m0 + m) * QDIM + k0 + kk];
            As[kk][m] = v;
        }
        #pragma unroll
        for (int idx = tid; idx < 16 * 64; idx += 256) {
            int kk = idx >> 6, n = idx & 63;
            Ws[kk][n] = W[(size_t)(k0 + kk) * QDIM + n0 + n];
        }
        __syncthreads();
        #pragma unroll
        for (int kk = 0; kk < 16; ++kk) {
            float4 a = *(const float4*)&As[kk][ty * 4];
            float4 w = *(const float4*)&Ws[kk][tx * 4];
            float av[4] = {a.x, a.y, a.z, a.w};
            float wv[4] = {w.x, w.y, w.z, w.w};
            #pragma unroll
            for (int ii = 0; ii < 4; ++ii)
                #pragma unroll
                for (int jj = 0; jj < 4; ++jj)
                    acc[ii][jj] += av[ii] * wv[jj];
        }
        __syncthreads();
    }
    if (MODE == 0) {
        float* C = (float*)dstv;
        #pragma unroll
        for (int ii = 0; ii < 4; ++ii) {
            int mm = m0 + ty * 4 + ii;
            if (mm >= M) continue;
            float4 v = make_float4(acc[ii][0], acc[ii][1], acc[ii][2], acc[ii][3]);
            float4 bv = *(const float4*)&bias[n0 + tx * 4];
            v.x += bv.x; v.y += bv.y; v.z += bv.z; v.w += bv.w;
            *(float4*)&C[(size_t)mm * QDIM + n0 + tx * 4] = v;
        }
    } else {
        const float sc = (MODE == 1) ? (0.15811388300841897f * 1.4426950408889634f) : 1.0f;
        ushort* D = (ushort*)dstv;
        #pragma unroll
        for (int ii = 0; ii < 4; ++ii) {
            int mm = m0 + ty * 4 + ii;
            if (mm >= M) continue;
            int b = mm / N_TOK, tok = mm - b * N_TOK;
            #pragma unroll
            for (int jj = 0; jj < 4; ++jj) {
                int n = n0 + tx * 4 + jj;
                int h = n / DHEAD, d = n - h * DHEAD;
                ushort val = f2bf(acc[ii][jj] * sc);
                if (MODE == 3)
                    D[((size_t)(b * HEADS + h) * 48 + d) * NPAD + tok] = val;
                else
                    D[((size_t)(b * HEADS + h) * NPAD + tok) * 64 + d] = val;
            }
        }
    }
}

// ------------------------------ mask predicate -------------------------------
__device__ __forceinline__ bool mask_ok(int i, int j, unsigned bi, unsigned bj) {
    if (j >= N_TOK) return false;
    if (i == j) return true;
    if (i < WH) {
        if (j < WH) return (bi & bj) != 0u;
        if (j >= WH + 4 * NOBJ) return true;
        int cI = j - WH;
        if ((unsigned)(cI - NOBJ) < (unsigned)(2 * NOBJ)) return true;
        int om = (cI < NOBJ) ? cI : cI - 3 * NOBJ;
        return ((bi >> om) & 1u) != 0u;
    }
    if (j >= WH) return true;
    if (i >= WH + 4 * NOBJ) return true;
    int rI = i - WH;
    if ((unsigned)(rI - NOBJ) < (unsigned)(2 * NOBJ)) return true;
    int om = (rI < NOBJ) ? rI : rI - 3 * NOBJ;
    return ((bj >> om) & 1u) != 0u;
}

// ------------------------------ fused attention ------------------------------
// Block: 4 waves x 16 queries = 64 query rows for one (b,h). K-tiles of 64.
__global__ __launch_bounds__(256) void k_attn(const ushort* __restrict__ Qb,
                                              const ushort* __restrict__ Kb,
                                              const ushort* __restrict__ Vt,
                                              const unsigned* __restrict__ bits,
                                              float* __restrict__ AO) {
    __shared__ __align__(16) char KtB[64 * 128];   // [key][64 bf16] swizzled
    __shared__ __align__(16) char VtB[48 * 128];   // [d][64 keys bf16] swizzled
    __shared__ __align__(16) char PsB[4 * 16 * 128]; // per-wave [q][64 keys bf16]
    __shared__ unsigned bJB[64];

    const int tid = threadIdx.x;
    const int lane = tid & 63, wv = tid >> 6;
    const int g = lane >> 4, c16 = lane & 15, l7 = lane & 7;
    const int bh = blockIdx.y, b = bh >> 3, h = bh & 7;
    const int qb_blk = blockIdx.x * 64;
    const int q0w = qb_blk + wv * 16;
    const int iq = q0w + c16;                 // this lane's query (S^T column)
    const bool vis_i = (qb_blk + 64 <= WH);

    // Q fragments: constant across the key loop (B-operand of S^T = K·Q^T)
    short8 qf0, qf1;
    {
        const ushort* qp = Qb + ((size_t)bh * NPAD + iq) * 64 + g * 8;
        qf0 = *(const short8*)(qp);
        qf1 = *(const short8*)(qp + 32);
    }
    const unsigned bitsI = bits[(size_t)b * NPAD + iq];

    const int sl0 = ((0 + g) ^ l7) * 16;      // k-step 0 16B-slot byte offset
    const int sl1 = ((4 + g) ^ l7) * 16;      // k-step 1
    const int rowb = c16 * 128;
    char* psw = PsB + wv * 2048;

    float m_run = NEGF, l_run = 0.f;
    f32x4 o0 = {0.f, 0.f, 0.f, 0.f}, o1 = o0, o2 = o0;

    for (int j0 = 0; j0 < NPAD; j0 += 64) {
        __syncthreads();
        // ---- stage K tile (8KB), Vt tile (6KB), key bits (256B) ----
        #pragma unroll
        for (int u = 0; u < 2; ++u) {
            int r0 = wv * 16 + u * 8;
            int key = r0 + (lane >> 3);
            int slot = (lane & 7) ^ (key & 7);
            GLD16(KtB + r0 * 128,
                  Kb + ((size_t)bh * NPAD + j0 + key) * 64 + slot * 8);
        }
        if (wv < 3) {
            #pragma unroll
            for (int u = 0; u < 2; ++u) {
                int d0r = wv * 16 + u * 8;
                int d = d0r + (lane >> 3);
                int slot = (lane & 7) ^ (d & 7);
                GLD16(VtB + d0r * 128,
                      Vt + ((size_t)bh * 48 + d) * NPAD + j0 + slot * 8);
            }
        } else {
            GLD4(bJB, bits + (size_t)b * NPAD + j0 + lane);
        }
        __syncthreads();

        // ---- S^T = K · Q^T : 8 MFMA ----
        f32x4 s4[4];
        #pragma unroll
        for (int kt = 0; kt < 4; ++kt) {
            const char* arow = KtB + kt * 2048 + rowb;
            f32x4 acc = {0.f, 0.f, 0.f, 0.f};
            acc = __builtin_amdgcn_mfma_f32_16x16x32_bf16(*(const short8*)(arow + sl0), qf0, acc, 0, 0, 0);
            acc = __builtin_amdgcn_mfma_f32_16x16x32_bf16(*(const short8*)(arow + sl1), qf1, acc, 0, 0, 0);
            s4[kt] = acc;
        }

        // ---- mask ----
        uintx4 bk[4];
        #pragma unroll
        for (int kt = 0; kt < 4; ++kt)
            bk[kt] = *(const uintx4*)&bJB[kt * 16 + g * 4];

        float sv[16];
        float pmax = NEGF;
        const bool vis_j = (j0 + 64 <= WH);
        if (vis_i && vis_j && (j0 != qb_blk)) {
            #pragma unroll
            for (int kt = 0; kt < 4; ++kt)
                #pragma unroll
                for (int r = 0; r < 4; ++r) {
                    float x = s4[kt][r];
                    x = ((bitsI & bk[kt][r]) != 0u) ? x : NEGF;
                    sv[kt * 4 + r] = x;
                    pmax = fmaxf(pmax, x);
                }
        } else if (vis_i && vis_j) {
            #pragma unroll
            for (int kt = 0; kt < 4; ++kt)
                #pragma unroll
                for (int r = 0; r < 4; ++r) {
                    int j = j0 + kt * 16 + g * 4 + r;
                    float x = s4[kt][r];
                    bool ok = ((bitsI & bk[kt][r]) != 0u) || (iq == j);
                    x = ok ? x : NEGF;
                    sv[kt * 4 + r] = x;
                    pmax = fmaxf(pmax, x);
                }
        } else {
            #pragma unroll
            for (int kt = 0; kt < 4; ++kt)
                #pragma unroll
                for (int r = 0; r < 4; ++r) {
                    int j = j0 + kt * 16 + g * 4 + r;
                    float x = s4[kt][r];
                    x = mask_ok(iq, j, bitsI, bk[kt][r]) ? x : NEGF;
                    sv[kt * 4 + r] = x;
                    pmax = fmaxf(pmax, x);
                }
        }

        // ---- online softmax (per query column c16; reduce over g) ----
        pmax = fmaxf(pmax, __shfl_xor(pmax, 16));
        pmax = fmaxf(pmax, __shfl_xor(pmax, 32));
        float mnew = fmaxf(m_run, pmax);
        float rs = __builtin_amdgcn_exp2f(m_run - mnew);
        m_run = mnew;
        float psum = 0.f;
        ushort pu[16];
        #pragma unroll
        for (int e = 0; e < 16; ++e) {
            float p = __builtin_amdgcn_exp2f(sv[e] - mnew);
            psum += p;
            pu[e] = f2bf(p);
        }
        psum += __shfl_xor(psum, 16);
        psum += __shfl_xor(psum, 32);
        l_run = l_run * rs + psum;

        // ---- write P^T rows to per-wave LDS (swizzled), 4x ds_write_b64 ----
        #pragma unroll
        for (int kt = 0; kt < 4; ++kt) {
            short4v w;
            w[0] = (short)pu[kt * 4 + 0];
            w[1] = (short)pu[kt * 4 + 1];
            w[2] = (short)pu[kt * 4 + 2];
            w[3] = (short)pu[kt * 4 + 3];
            *(short4v*)(psw + rowb + ((32 * kt + 8 * g) ^ (l7 << 4))) = w;
        }

        // ---- rescale O accumulators (rows = queries g*4+r) ----
        float rr0 = __shfl(rs, g * 4 + 0);
        float rr1 = __shfl(rs, g * 4 + 1);
        float rr2 = __shfl(rs, g * 4 + 2);
        float rr3 = __shfl(rs, g * 4 + 3);
        o0[0] *= rr0; o0[1] *= rr1; o0[2] *= rr2; o0[3] *= rr3;
        o1[0] *= rr0; o1[1] *= rr1; o1[2] *= rr2; o1[3] *= rr3;
        o2[0] *= rr0; o2[1] *= rr1; o2[2] *= rr2; o2[3] *= rr3;

        // ---- PV: O += P · V, 6 MFMA ----
        short8 pa0 = *(const short8*)(psw + rowb + sl0);
        short8 pa1 = *(const short8*)(psw + rowb + sl1);
        {
            const char* v0r = VtB + 0 * 2048 + rowb;
            const char* v1r = VtB + 1 * 2048 + rowb;
            const char* v2r = VtB + 2 * 2048 + rowb;
            o0 = __builtin_amdgcn_mfma_f32_16x16x32_bf16(pa0, *(const short8*)(v0r + sl0), o0, 0, 0, 0);
            o0 = __builtin_amdgcn_mfma_f32_16x16x32_bf16(pa1, *(const short8*)(v0r + sl1), o0, 0, 0, 0);
            o1 = __builtin_amdgcn_mfma_f32_16x16x32_bf16(pa0, *(const short8*)(v1r + sl0), o1, 0, 0, 0);
            o1 = __builtin_amdgcn_mfma_f32_16x16x32_bf16(pa1, *(const short8*)(v1r + sl1), o1, 0, 0, 0);
            o2 = __builtin_amdgcn_mfma_f32_16x16x32_bf16(pa0, *(const short8*)(v2r + sl0), o2, 0, 0, 0);
            o2 = __builtin_amdgcn_mfma_f32_16x16x32_bf16(pa1, *(const short8*)(v2r + sl1), o2, 0, 0, 0);
        }
    }

    // ---- epilogue: divide by l and store (rows g*4+r, cols nt*16+c16) ----
    float lr0 = __shfl(l_run, g * 4 + 0);
    float lr1 = __shfl(l_run, g * 4 + 1);
    float lr2 = __shfl(l_run, g * 4 + 2);
    float lr3 = __shfl(l_run, g * 4 + 3);
    float inv[4] = {1.f / lr0, 1.f / lr1, 1.f / lr2, 1.f / lr3};
    #pragma unroll
    for (int r = 0; r < 4; ++r) {
        int qrow = q0w + g * 4 + r;
        if (qrow >= N_TOK) continue;
        float* dst = AO + ((size_t)(b * N_TOK + qrow)) * INNER + h * DHEAD;
        dst[c16]      = o0[r] * inv[r];
        dst[16 + c16] = o1[r] * inv[r];
        if (c16 < 8) dst[32 + c16] = o2[r] * inv[r];
    }
}

// --------------------------------- launcher ----------------------------------
extern "C" void kernel_launch(void* const* d_in, const int* in_sizes, int n_in,
                              void* d_out, int out_size, void* d_ws, size_t ws_size,
                              hipStream_t stream) {
    const float* x   = (const float*)d_in[0];
    const float* att = (const float*)d_in[1];
    const float* Wq  = (const float*)d_in[2];
    const float* Wk  = (const float*)d_in[3];
    const float* Wv  = (const float*)d_in[4];
    const float* Wo  = (const float*)d_in[5];
    const float* bo  = (const float*)d_in[6];
    float* out = (float*)d_out;

    char* w = (char*)d_ws;
    unsigned* bits = (unsigned*)w;                         // 64 KB reserved
    ushort* Qb = (ushort*)(w + 65536);                     // 16*4288*64 bf16
    ushort* Kb = Qb + (size_t)16 * NPAD * 64;
    ushort* Vt = Kb + (size_t)16 * NPAD * 64;              // 16*48*4288 bf16
    float*  AO = (float*)(Vt + (size_t)16 * 48 * NPAD);

    // zero bf16 staging region (Qb..Vt contiguous)
    {
        size_t bytes = ((size_t)16 * NPAD * 64 * 2) * 2 + (size_t)16 * 48 * NPAD * 2;
        int n16 = (int)(bytes / 16);
        k_zero<<<2048, 256, 0, stream>>>((u64x2*)Qb, n16);
    }
    k_bits<<<(BB * NPAD + 255) / 256, 256, 0, stream>>>(att, bits);

    dim3 gg((M_ROWS + 63) / 64, QDIM / 64);
    k_gemm<1><<<gg, 256, 0, stream>>>(x, Wq, nullptr, Qb, M_ROWS);
    k_gemm<2><<<gg, 256, 0, stream>>>(x, Wk, nullptr, Kb, M_ROWS);
    k_gemm<3><<<gg, 256, 0, stream>>>(x, Wv, nullptr, Vt, M_ROWS);

    dim3 ga(NPAD / 64, BB * HEADS);
    k_attn<<<ga, 256, 0, stream>>>(Qb, Kb, Vt, bits, AO);

    k_gemm<0><<<gg, 256, 0, stream>>>(AO, Wo, bo, out, M_ROWS);
}

// Round 3
// 286.511 us; speedup vs baseline: 7.0546x; 1.6573x over previous
//
#include <hip/hip_runtime.h>
#include <hip/hip_bf16.h>

#define BB 2
#define N_TOK 4280
#define NPAD 4288
#define MPAD 8576
#define WH 4096
#define NOBJ 30
#define QDIM 320
#define HEADS 8
#define DHEAD 40
#define M_ROWS (BB * N_TOK)   /* 8560 */
#define NEGF (-3.0e38f)
#define NT_K (NPAD / 64)      /* 67 */

typedef __attribute__((ext_vector_type(8))) short short8;
typedef __attribute__((ext_vector_type(4))) short short4v;
typedef __attribute__((ext_vector_type(4))) float f32x4;
typedef __attribute__((ext_vector_type(4))) unsigned uintx4;
typedef __attribute__((ext_vector_type(2))) unsigned long long u64x2;

#define GLD16(lds, g) __builtin_amdgcn_global_load_lds( \
    (const __attribute__((address_space(1))) unsigned*)(g), \
    (__attribute__((address_space(3))) unsigned*)(lds), 16, 0, 0)
#define GLD4(lds, g) __builtin_amdgcn_global_load_lds( \
    (const __attribute__((address_space(1))) unsigned*)(g), \
    (__attribute__((address_space(3))) unsigned*)(lds), 4, 0, 0)

__device__ __forceinline__ ushort f2bf(float x) {
    union { __hip_bfloat16 h; ushort u; } cv;
    cv.h = __float2bfloat16(x);
    return cv.u;
}

// -------------------- zero Qb (head-dim + token padding) --------------------
__global__ void k_zero(u64x2* __restrict__ p, int n16) {
    int stride = gridDim.x * blockDim.x;
    u64x2 z = {0ull, 0ull};
    for (int i = blockIdx.x * blockDim.x + threadIdx.x; i < n16; i += stride)
        p[i] = z;
}

// -------------------- pack object masks into 30-bit words -------------------
__global__ void k_bits(const float* __restrict__ att, unsigned* __restrict__ bits) {
    int gid = blockIdx.x * blockDim.x + threadIdx.x;
    if (gid >= BB * NPAD) return;
    int b = gid / NPAD, i = gid - b * NPAD;
    unsigned v = 0;
    if (i < WH) {
        const float* base = att + (size_t)b * NOBJ * WH + i;
        #pragma unroll
        for (int o = 0; o < NOBJ; ++o)
            if (base[(size_t)o * WH] > 0.5f) v |= (1u << o);
    }
    bits[gid] = v;
}

// -------------------- x -> bf16 ---------------------------------------------
__global__ void k_xcvt(const float* __restrict__ x, ushort* __restrict__ xb) {
    int i = blockIdx.x * blockDim.x + threadIdx.x;
    if (i >= M_ROWS * QDIM / 8) return;
    float4 v0 = ((const float4*)x)[i * 2];
    float4 v1 = ((const float4*)x)[i * 2 + 1];
    short8 o;
    o[0] = (short)f2bf(v0.x); o[1] = (short)f2bf(v0.y);
    o[2] = (short)f2bf(v0.z); o[3] = (short)f2bf(v0.w);
    o[4] = (short)f2bf(v1.x); o[5] = (short)f2bf(v1.y);
    o[6] = (short)f2bf(v1.z); o[7] = (short)f2bf(v1.w);
    ((short8*)xb)[i] = o;
}

// ------ weights -> bf16, transposed: WtAll[1280][320]; rows 0-959 = QKV^T ---
__global__ __launch_bounds__(256) void k_wcvt(const float* __restrict__ Wq,
                                              const float* __restrict__ Wk,
                                              const float* __restrict__ Wv,
                                              const float* __restrict__ Wo,
                                              ushort* __restrict__ WtAll) {
    __shared__ float T[32][33];
    const int k0 = blockIdx.x * 32;
    const int np0 = blockIdx.y * 32;
    const float SC = 0.15811388300841897f * 1.4426950408889634f; // scale*log2e
    const float* src; int n0; float sc = 1.f;
    if (np0 < 320)      { src = Wq; n0 = np0;       sc = SC; }
    else if (np0 < 640) { src = Wk; n0 = np0 - 320; }
    else if (np0 < 960) { src = Wv; n0 = np0 - 640; }
    else                { src = Wo; n0 = np0 - 960; }
    const int tid = threadIdx.x;
    #pragma unroll
    for (int it = 0; it < 4; ++it) {
        int idx = tid + it * 256;
        int r = idx >> 5, c = idx & 31;
        T[r][c] = src[(size_t)(k0 + r) * QDIM + n0 + c];
    }
    __syncthreads();
    #pragma unroll
    for (int it = 0; it < 4; ++it) {
        int idx = tid + it * 256;
        int rr = idx >> 5, cc = idx & 31;
        WtAll[(size_t)(np0 + rr) * QDIM + k0 + cc] = f2bf(T[cc][rr] * sc);
    }
}

// -------------------- MFMA GEMM: C[m][n] = A[m][:] . Wt[n][:] ---------------
// IS_OUT=0: fused QKV (grid.y = 15), epilogue scatters to Qb/Kb/Vt bf16.
// IS_OUT=1: out-proj (grid.y = 5), f32 out + bias.
template<int IS_OUT>
__global__ __launch_bounds__(256) void k_mm(const ushort* __restrict__ A,
                                            const ushort* __restrict__ Wt,
                                            const float* __restrict__ bias,
                                            ushort* __restrict__ Qb,
                                            ushort* __restrict__ Kb,
                                            ushort* __restrict__ Vt,
                                            float* __restrict__ Cout) {
    __shared__ __align__(16) char Ab[2][8192];
    __shared__ __align__(16) char Bb[2][8192];
    const int tid = threadIdx.x, lane = tid & 63, wv = tid >> 6;
    const int g = lane >> 4, c16 = lane & 15, l7 = lane & 7;
    const int rsub = lane >> 3, slotx = lane & 7;
    const int m0 = blockIdx.x * 64;
    const int nt = blockIdx.y;

    f32x4 acc[4] = {{0,0,0,0},{0,0,0,0},{0,0,0,0},{0,0,0,0}};

    auto STAGE = [&](int ks, int bufi) {
        const int k0 = ks * 64;
        #pragma unroll
        for (int u = 0; u < 2; ++u) {
            int r0 = wv * 16 + u * 8;
            int row = r0 + rsub;
            int slot = slotx ^ (row & 7);
            GLD16(Ab[bufi] + r0 * 128, A + (size_t)(m0 + row) * QDIM + k0 + slot * 8);
            GLD16(Bb[bufi] + r0 * 128, Wt + (size_t)(nt * 64 + row) * QDIM + k0 + slot * 8);
        }
    };

    const int sl0 = (g ^ l7) * 16, sl1 = ((4 + g) ^ l7) * 16;

    STAGE(0, 0);
    __syncthreads();
    int cur = 0;
    for (int ks = 0; ks < 5; ++ks) {
        if (ks < 4) STAGE(ks + 1, cur ^ 1);
        const char* bbase = Bb[cur] + (wv * 16 + c16) * 128;
        short8 bf0 = *(const short8*)(bbase + sl0);
        short8 bf1 = *(const short8*)(bbase + sl1);
        #pragma unroll
        for (int mi = 0; mi < 4; ++mi) {
            const char* abase = Ab[cur] + (mi * 16 + c16) * 128;
            acc[mi] = __builtin_amdgcn_mfma_f32_16x16x32_bf16(*(const short8*)(abase + sl0), bf0, acc[mi], 0, 0, 0);
            acc[mi] = __builtin_amdgcn_mfma_f32_16x16x32_bf16(*(const short8*)(abase + sl1), bf1, acc[mi], 0, 0, 0);
        }
        __syncthreads();
        cur ^= 1;
    }

    const int ng = nt * 64 + wv * 16 + c16;
    if (IS_OUT) {
        float bv = bias[ng];
        #pragma unroll
        for (int mi = 0; mi < 4; ++mi)
            #pragma unroll
            for (int r = 0; r < 4; ++r) {
                int m = m0 + mi * 16 + g * 4 + r;
                if (m < M_ROWS) Cout[(size_t)m * QDIM + ng] = acc[mi][r] + bv;
            }
    } else {
        int p = ng / QDIM, nn = ng - p * QDIM;
        int h = nn / DHEAD, d = nn - h * DHEAD;
        if (p == 2) {
            #pragma unroll
            for (int mi = 0; mi < 4; ++mi) {
                int m = m0 + mi * 16 + g * 4;        // 4-aligned; N_TOK%4==0
                if (m >= M_ROWS) continue;
                int b = m / N_TOK, tok = m - b * N_TOK;
                short4v w4;
                w4[0] = (short)f2bf(acc[mi][0]);
                w4[1] = (short)f2bf(acc[mi][1]);
                w4[2] = (short)f2bf(acc[mi][2]);
                w4[3] = (short)f2bf(acc[mi][3]);
                *(short4v*)(Vt + ((size_t)(b * HEADS + h) * 48 + d) * NPAD + tok) = w4;
            }
        } else {
            ushort* base = (p == 0) ? Qb : Kb;
            #pragma unroll
            for (int mi = 0; mi < 4; ++mi)
                #pragma unroll
                for (int r = 0; r < 4; ++r) {
                    int m = m0 + mi * 16 + g * 4 + r;
                    if (m >= M_ROWS) continue;
                    int b = m / N_TOK, tok = m - b * N_TOK;
                    base[((size_t)(b * HEADS + h) * NPAD + tok) * 64 + d] = f2bf(acc[mi][r]);
                }
        }
    }
}

// ------------------------------ mask predicate ------------------------------
__device__ __forceinline__ bool mask_ok(int i, int j, unsigned bi, unsigned bj) {
    if (j >= N_TOK) return false;
    if (i == j) return true;
    if (i < WH) {
        if (j < WH) return (bi & bj) != 0u;
        if (j >= WH + 4 * NOBJ) return true;
        int cI = j - WH;
        if ((unsigned)(cI - NOBJ) < (unsigned)(2 * NOBJ)) return true;
        int om = (cI < NOBJ) ? cI : cI - 3 * NOBJ;
        return ((bi >> om) & 1u) != 0u;
    }
    if (j >= WH) return true;
    if (i >= WH + 4 * NOBJ) return true;
    int rI = i - WH;
    if ((unsigned)(rI - NOBJ) < (unsigned)(2 * NOBJ)) return true;
    int om = (rI < NOBJ) ? rI : rI - 3 * NOBJ;
    return ((bj >> om) & 1u) != 0u;
}

// --------------------- fused attention (double-buffered) --------------------
__global__ __launch_bounds__(256) void k_attn(const ushort* __restrict__ Qb,
                                              const ushort* __restrict__ Kb,
                                              const ushort* __restrict__ Vt,
                                              const unsigned* __restrict__ bits,
                                              ushort* __restrict__ AOb) {
    __shared__ __align__(16) char KtB[2][8192];
    __shared__ __align__(16) char VtB[2][6144];
    __shared__ __align__(16) char PsB[8192];
    __shared__ __align__(16) unsigned bJB[2][64];

    const int tid = threadIdx.x;
    const int lane = tid & 63, wv = tid >> 6;
    const int g = lane >> 4, c16 = lane & 15, l7 = lane & 7;
    const int rsub = lane >> 3, slotx = lane & 7;

    // XCD-chunked bijective swizzle: 1072 = 8 * 134
    const int bid = blockIdx.x;
    const int logical = (bid & 7) * 134 + (bid >> 3);
    const int bh = logical / NT_K, qt = logical - bh * NT_K;
    const int b = bh >> 3;
    const int qb_blk = qt * 64;
    const int q0w = qb_blk + wv * 16;
    const int iq = q0w + c16;
    const bool vis_i = (qb_blk + 64 <= WH);

    short8 qf0, qf1;
    {
        const ushort* qp = Qb + ((size_t)bh * NPAD + iq) * 64 + g * 8;
        qf0 = *(const short8*)(qp);
        qf1 = *(const short8*)(qp + 32);
    }
    const unsigned bitsI = bits[(size_t)b * NPAD + iq];

    const int sl0 = (g ^ l7) * 16;
    const int sl1 = ((4 + g) ^ l7) * 16;
    const int rowb = c16 * 128;
    char* psw = PsB + wv * 2048;

    auto STAGE = [&](int t, int bufi) {
        const int j0 = t * 64;
        #pragma unroll
        for (int u = 0; u < 2; ++u) {
            int r0 = wv * 16 + u * 8;
            int key = r0 + rsub;
            int slot = slotx ^ (key & 7);
            GLD16(KtB[bufi] + r0 * 128,
                  Kb + ((size_t)bh * NPAD + j0 + key) * 64 + slot * 8);
        }
        if (wv < 3) {
            #pragma unroll
            for (int u = 0; u < 2; ++u) {
                int d0r = wv * 16 + u * 8;
                int d = d0r + rsub;
                int slot = slotx ^ (d & 7);
                GLD16(VtB[bufi] + d0r * 128,
                      Vt + ((size_t)bh * 48 + d) * NPAD + j0 + slot * 8);
            }
        } else {
            GLD4(bJB[bufi], bits + (size_t)b * NPAD + j0 + lane);
        }
    };

    float m_run = NEGF, l_run = 0.f;
    f32x4 o0 = {0.f, 0.f, 0.f, 0.f}, o1 = o0, o2 = o0;

    STAGE(0, 0);
    __syncthreads();
    int cur = 0;
    for (int t = 0; t < NT_K; ++t) {
        const int j0 = t * 64;
        if (t + 1 < NT_K) STAGE(t + 1, cur ^ 1);

        // ---- S^T = K . Q^T : 8 MFMA ----
        f32x4 s4[4];
        #pragma unroll
        for (int kt = 0; kt < 4; ++kt) {
            const char* arow = KtB[cur] + kt * 2048 + rowb;
            f32x4 a = {0.f, 0.f, 0.f, 0.f};
            a = __builtin_amdgcn_mfma_f32_16x16x32_bf16(*(const short8*)(arow + sl0), qf0, a, 0, 0, 0);
            a = __builtin_amdgcn_mfma_f32_16x16x32_bf16(*(const short8*)(arow + sl1), qf1, a, 0, 0, 0);
            s4[kt] = a;
        }

        // ---- mask ----
        uintx4 bk[4];
        #pragma unroll
        for (int kt = 0; kt < 4; ++kt)
            bk[kt] = *(const uintx4*)&bJB[cur][kt * 16 + g * 4];

        float sv[16];
        float pmax = NEGF;
        const bool vis_j = (j0 + 64 <= WH);
        if (vis_i && vis_j && (j0 != qb_blk)) {
            #pragma unroll
            for (int kt = 0; kt < 4; ++kt)
                #pragma unroll
                for (int r = 0; r < 4; ++r) {
                    float x = s4[kt][r];
                    x = ((bitsI & bk[kt][r]) != 0u) ? x : NEGF;
                    sv[kt * 4 + r] = x;
                    pmax = fmaxf(pmax, x);
                }
        } else if (vis_i && vis_j) {
            #pragma unroll
            for (int kt = 0; kt < 4; ++kt)
                #pragma unroll
                for (int r = 0; r < 4; ++r) {
                    int j = j0 + kt * 16 + g * 4 + r;
                    float x = s4[kt][r];
                    bool ok = ((bitsI & bk[kt][r]) != 0u) || (iq == j);
                    x = ok ? x : NEGF;
                    sv[kt * 4 + r] = x;
                    pmax = fmaxf(pmax, x);
                }
        } else {
            #pragma unroll
            for (int kt = 0; kt < 4; ++kt)
                #pragma unroll
                for (int r = 0; r < 4; ++r) {
                    int j = j0 + kt * 16 + g * 4 + r;
                    float x = s4[kt][r];
                    x = mask_ok(iq, j, bitsI, bk[kt][r]) ? x : NEGF;
                    sv[kt * 4 + r] = x;
                    pmax = fmaxf(pmax, x);
                }
        }

        // ---- online softmax (per query c16, reduce over g) ----
        pmax = fmaxf(pmax, __shfl_xor(pmax, 16));
        pmax = fmaxf(pmax, __shfl_xor(pmax, 32));
        float mnew = fmaxf(m_run, pmax);
        float rs = __builtin_amdgcn_exp2f(m_run - mnew);
        m_run = mnew;
        float psum = 0.f;
        ushort pu[16];
        #pragma unroll
        for (int e = 0; e < 16; ++e) {
            float p = __builtin_amdgcn_exp2f(sv[e] - mnew);
            psum += p;
            pu[e] = f2bf(p);
        }
        psum += __shfl_xor(psum, 16);
        psum += __shfl_xor(psum, 32);
        l_run = l_run * rs + psum;

        // ---- P^T -> per-wave LDS (swizzled) ----
        #pragma unroll
        for (int kt = 0; kt < 4; ++kt) {
            short4v w;
            w[0] = (short)pu[kt * 4 + 0];
            w[1] = (short)pu[kt * 4 + 1];
            w[2] = (short)pu[kt * 4 + 2];
            w[3] = (short)pu[kt * 4 + 3];
            *(short4v*)(psw + rowb + ((32 * kt + 8 * g) ^ (l7 << 4))) = w;
        }

        // ---- rescale O ----
        float rr0 = __shfl(rs, g * 4 + 0);
        float rr1 = __shfl(rs, g * 4 + 1);
        float rr2 = __shfl(rs, g * 4 + 2);
        float rr3 = __shfl(rs, g * 4 + 3);
        o0[0] *= rr0; o0[1] *= rr1; o0[2] *= rr2; o0[3] *= rr3;
        o1[0] *= rr0; o1[1] *= rr1; o1[2] *= rr2; o1[3] *= rr3;
        o2[0] *= rr0; o2[1] *= rr1; o2[2] *= rr2; o2[3] *= rr3;

        // ---- PV: 6 MFMA ----
        short8 pa0 = *(const short8*)(psw + rowb + sl0);
        short8 pa1 = *(const short8*)(psw + rowb + sl1);
        {
            const char* v0r = VtB[cur] + 0 * 2048 + rowb;
            const char* v1r = VtB[cur] + 1 * 2048 + rowb;
            const char* v2r = VtB[cur] + 2 * 2048 + rowb;
            o0 = __builtin_amdgcn_mfma_f32_16x16x32_bf16(pa0, *(const short8*)(v0r + sl0), o0, 0, 0, 0);
            o0 = __builtin_amdgcn_mfma_f32_16x16x32_bf16(pa1, *(const short8*)(v0r + sl1), o0, 0, 0, 0);
            o1 = __builtin_amdgcn_mfma_f32_16x16x32_bf16(pa0, *(const short8*)(v1r + sl0), o1, 0, 0, 0);
            o1 = __builtin_amdgcn_mfma_f32_16x16x32_bf16(pa1, *(const short8*)(v1r + sl1), o1, 0, 0, 0);
            o2 = __builtin_amdgcn_mfma_f32_16x16x32_bf16(pa0, *(const short8*)(v2r + sl0), o2, 0, 0, 0);
            o2 = __builtin_amdgcn_mfma_f32_16x16x32_bf16(pa1, *(const short8*)(v2r + sl1), o2, 0, 0, 0);
        }
        __syncthreads();
        cur ^= 1;
    }

    // ---- epilogue: /l, bf16 store to AOb ----
    float lr0 = __shfl(l_run, g * 4 + 0);
    float lr1 = __shfl(l_run, g * 4 + 1);
    float lr2 = __shfl(l_run, g * 4 + 2);
    float lr3 = __shfl(l_run, g * 4 + 3);
    float inv[4] = {1.f / lr0, 1.f / lr1, 1.f / lr2, 1.f / lr3};
    const int h = bh & 7;
    #pragma unroll
    for (int r = 0; r < 4; ++r) {
        int qrow = q0w + g * 4 + r;
        if (qrow >= N_TOK) continue;
        ushort* dst = AOb + (size_t)(b * N_TOK + qrow) * QDIM + h * DHEAD;
        dst[c16]      = f2bf(o0[r] * inv[r]);
        dst[16 + c16] = f2bf(o1[r] * inv[r]);
        if (c16 < 8) dst[32 + c16] = f2bf(o2[r] * inv[r]);
    }
}

// --------------------------------- launcher ---------------------------------
extern "C" void kernel_launch(void* const* d_in, const int* in_sizes, int n_in,
                              void* d_out, int out_size, void* d_ws, size_t ws_size,
                              hipStream_t stream) {
    const float* x   = (const float*)d_in[0];
    const float* att = (const float*)d_in[1];
    const float* Wq  = (const float*)d_in[2];
    const float* Wk  = (const float*)d_in[3];
    const float* Wv  = (const float*)d_in[4];
    const float* Wo  = (const float*)d_in[5];
    const float* bo  = (const float*)d_in[6];
    float* out = (float*)d_out;

    char* w = (char*)d_ws;
    unsigned* bits = (unsigned*)w;
    size_t off = 65536;
    ushort* xb    = (ushort*)(w + off); off += (size_t)MPAD * QDIM * 2;
    ushort* WtAll = (ushort*)(w + off); off += (size_t)1280 * QDIM * 2;
    ushort* Qb    = (ushort*)(w + off); off += (size_t)16 * NPAD * 64 * 2;
    ushort* Kb    = (ushort*)(w + off); off += (size_t)16 * NPAD * 64 * 2;
    ushort* Vt    = (ushort*)(w + off); off += (size_t)16 * 48 * NPAD * 2;
    ushort* AOb   = (ushort*)(w + off);

    k_zero<<<1024, 256, 0, stream>>>((u64x2*)Qb, (int)((size_t)16 * NPAD * 64 * 2 / 16));
    k_bits<<<(BB * NPAD + 255) / 256, 256, 0, stream>>>(att, bits);
    k_xcvt<<<(M_ROWS * QDIM / 8 + 255) / 256, 256, 0, stream>>>(x, xb);
    k_wcvt<<<dim3(10, 40), 256, 0, stream>>>(Wq, Wk, Wv, Wo, WtAll);

    k_mm<0><<<dim3(MPAD / 64, 15), 256, 0, stream>>>(xb, WtAll, nullptr, Qb, Kb, Vt, nullptr);
    k_attn<<<1072, 256, 0, stream>>>(Qb, Kb, Vt, bits, AOb);
    k_mm<1><<<dim3(MPAD / 64, 5), 256, 0, stream>>>(AOb, WtAll + 960 * QDIM, bo,
                                                    nullptr, nullptr, nullptr, out);
}

// Round 4
// 278.895 us; speedup vs baseline: 7.2473x; 1.0273x over previous
//
#include <hip/hip_runtime.h>
#include <hip/hip_bf16.h>

#define BB 2
#define N_TOK 4280
#define NPAD 4352            /* 34 * 128 */
#define MPAD 8576
#define WH 4096
#define NOBJ 30
#define QDIM 320
#define HEADS 8
#define DHEAD 40
#define M_ROWS (BB * N_TOK)  /* 8560 */
#define NEGF (-3.0e38f)
#define NT128 (NPAD / 128)   /* 34 */
#define NQT (NPAD / 64)      /* 68 */

typedef __attribute__((ext_vector_type(8))) short short8;
typedef __attribute__((ext_vector_type(4))) short short4v;
typedef __attribute__((ext_vector_type(4))) float f32x4;
typedef __attribute__((ext_vector_type(4))) unsigned uintx4;
typedef __attribute__((ext_vector_type(2))) unsigned long long u64x2;

#define GLD16(lds, g) __builtin_amdgcn_global_load_lds( \
    (const __attribute__((address_space(1))) unsigned*)(g), \
    (__attribute__((address_space(3))) unsigned*)(lds), 16, 0, 0)
#define GLD4(lds, g) __builtin_amdgcn_global_load_lds( \
    (const __attribute__((address_space(1))) unsigned*)(g), \
    (__attribute__((address_space(3))) unsigned*)(lds), 4, 0, 0)

__device__ __forceinline__ ushort f2bf(float x) {
    union { __hip_bfloat16 h; ushort u; } cv;
    cv.h = __float2bfloat16(x);
    return cv.u;
}

// -------------------- zero Qb (head-dim + token padding) --------------------
__global__ void k_zero(u64x2* __restrict__ p, int n16) {
    int stride = gridDim.x * blockDim.x;
    u64x2 z = {0ull, 0ull};
    for (int i = blockIdx.x * blockDim.x + threadIdx.x; i < n16; i += stride)
        p[i] = z;
}

// -------------------- pack object masks into 30-bit words -------------------
__global__ void k_bits(const float* __restrict__ att, unsigned* __restrict__ bits) {
    int gid = blockIdx.x * blockDim.x + threadIdx.x;
    if (gid >= BB * NPAD) return;
    int b = gid / NPAD, i = gid - b * NPAD;
    unsigned v = 0;
    if (i < WH) {
        const float* base = att + (size_t)b * NOBJ * WH + i;
        #pragma unroll
        for (int o = 0; o < NOBJ; ++o)
            if (base[(size_t)o * WH] > 0.5f) v |= (1u << o);
    }
    bits[gid] = v;
}

// -------------------- x -> bf16 ---------------------------------------------
__global__ void k_xcvt(const float* __restrict__ x, ushort* __restrict__ xb) {
    int i = blockIdx.x * blockDim.x + threadIdx.x;
    if (i >= M_ROWS * QDIM / 8) return;
    float4 v0 = ((const float4*)x)[i * 2];
    float4 v1 = ((const float4*)x)[i * 2 + 1];
    short8 o;
    o[0] = (short)f2bf(v0.x); o[1] = (short)f2bf(v0.y);
    o[2] = (short)f2bf(v0.z); o[3] = (short)f2bf(v0.w);
    o[4] = (short)f2bf(v1.x); o[5] = (short)f2bf(v1.y);
    o[6] = (short)f2bf(v1.z); o[7] = (short)f2bf(v1.w);
    ((short8*)xb)[i] = o;
}

// ------ weights -> bf16, transposed: WtAll[1280][320]; rows 0-959 = QKV^T ---
__global__ __launch_bounds__(256) void k_wcvt(const float* __restrict__ Wq,
                                              const float* __restrict__ Wk,
                                              const float* __restrict__ Wv,
                                              const float* __restrict__ Wo,
                                              ushort* __restrict__ WtAll) {
    __shared__ float T[32][33];
    const int k0 = blockIdx.x * 32;
    const int np0 = blockIdx.y * 32;
    const float SC = 0.15811388300841897f * 1.4426950408889634f; // scale*log2e
    const float* src; int n0; float sc = 1.f;
    if (np0 < 320)      { src = Wq; n0 = np0;       sc = SC; }
    else if (np0 < 640) { src = Wk; n0 = np0 - 320; }
    else if (np0 < 960) { src = Wv; n0 = np0 - 640; }
    else                { src = Wo; n0 = np0 - 960; }
    const int tid = threadIdx.x;
    #pragma unroll
    for (int it = 0; it < 4; ++it) {
        int idx = tid + it * 256;
        int r = idx >> 5, c = idx & 31;
        T[r][c] = src[(size_t)(k0 + r) * QDIM + n0 + c];
    }
    __syncthreads();
    #pragma unroll
    for (int it = 0; it < 4; ++it) {
        int idx = tid + it * 256;
        int rr = idx >> 5, cc = idx & 31;
        WtAll[(size_t)(np0 + rr) * QDIM + k0 + cc] = f2bf(T[cc][rr] * sc);
    }
}

// -------------------- MFMA GEMM: C[m][n] = A[m][:] . Wt[n][:] ---------------
template<int IS_OUT>
__global__ __launch_bounds__(256) void k_mm(const ushort* __restrict__ A,
                                            const ushort* __restrict__ Wt,
                                            const float* __restrict__ bias,
                                            ushort* __restrict__ Qb,
                                            ushort* __restrict__ Kb,
                                            ushort* __restrict__ Vt,
                                            float* __restrict__ Cout) {
    __shared__ __align__(16) char Ab[2][8192];
    __shared__ __align__(16) char Bb[2][8192];
    const int tid = threadIdx.x, lane = tid & 63, wv = tid >> 6;
    const int g = lane >> 4, c16 = lane & 15, l7 = lane & 7;
    const int rsub = lane >> 3, slotx = lane & 7;
    const int m0 = blockIdx.x * 64;
    const int nt = blockIdx.y;

    f32x4 acc[4] = {{0,0,0,0},{0,0,0,0},{0,0,0,0},{0,0,0,0}};

    auto STAGE = [&](int ks, int bufi) {
        const int k0 = ks * 64;
        #pragma unroll
        for (int u = 0; u < 2; ++u) {
            int r0 = wv * 16 + u * 8;
            int row = r0 + rsub;
            int slot = slotx ^ (row & 7);
            GLD16(Ab[bufi] + r0 * 128, A + (size_t)(m0 + row) * QDIM + k0 + slot * 8);
            GLD16(Bb[bufi] + r0 * 128, Wt + (size_t)(nt * 64 + row) * QDIM + k0 + slot * 8);
        }
    };

    const int sl0 = (g ^ l7) * 16, sl1 = ((4 + g) ^ l7) * 16;

    STAGE(0, 0);
    __syncthreads();
    int cur = 0;
    for (int ks = 0; ks < 5; ++ks) {
        if (ks < 4) STAGE(ks + 1, cur ^ 1);
        const char* bbase = Bb[cur] + (wv * 16 + c16) * 128;
        short8 bf0 = *(const short8*)(bbase + sl0);
        short8 bf1 = *(const short8*)(bbase + sl1);
        #pragma unroll
        for (int mi = 0; mi < 4; ++mi) {
            const char* abase = Ab[cur] + (mi * 16 + c16) * 128;
            acc[mi] = __builtin_amdgcn_mfma_f32_16x16x32_bf16(*(const short8*)(abase + sl0), bf0, acc[mi], 0, 0, 0);
            acc[mi] = __builtin_amdgcn_mfma_f32_16x16x32_bf16(*(const short8*)(abase + sl1), bf1, acc[mi], 0, 0, 0);
        }
        __syncthreads();
        cur ^= 1;
    }

    const int ng = nt * 64 + wv * 16 + c16;
    if (IS_OUT) {
        float bv = bias[ng];
        #pragma unroll
        for (int mi = 0; mi < 4; ++mi)
            #pragma unroll
            for (int r = 0; r < 4; ++r) {
                int m = m0 + mi * 16 + g * 4 + r;
                if (m < M_ROWS) Cout[(size_t)m * QDIM + ng] = acc[mi][r] + bv;
            }
    } else {
        int p = ng / QDIM, nn = ng - p * QDIM;
        int h = nn / DHEAD, d = nn - h * DHEAD;
        if (p == 2) {
            #pragma unroll
            for (int mi = 0; mi < 4; ++mi) {
                int m = m0 + mi * 16 + g * 4;        // 4-aligned; N_TOK%4==0
                if (m >= M_ROWS) continue;
                int b = m / N_TOK, tok = m - b * N_TOK;
                short4v w4;
                w4[0] = (short)f2bf(acc[mi][0]);
                w4[1] = (short)f2bf(acc[mi][1]);
                w4[2] = (short)f2bf(acc[mi][2]);
                w4[3] = (short)f2bf(acc[mi][3]);
                *(short4v*)(Vt + ((size_t)(b * HEADS + h) * 48 + d) * NPAD + tok) = w4;
            }
        } else {
            ushort* base = (p == 0) ? Qb : Kb;
            #pragma unroll
            for (int mi = 0; mi < 4; ++mi)
                #pragma unroll
                for (int r = 0; r < 4; ++r) {
                    int m = m0 + mi * 16 + g * 4 + r;
                    if (m >= M_ROWS) continue;
                    int b = m / N_TOK, tok = m - b * N_TOK;
                    base[((size_t)(b * HEADS + h) * NPAD + tok) * 64 + d] = f2bf(acc[mi][r]);
                }
        }
    }
}

// ------------------------------ mask predicate ------------------------------
__device__ __forceinline__ bool mask_ok(int i, int j, unsigned bi, unsigned bj) {
    if (j >= N_TOK) return false;
    if (i == j) return true;
    if (i < WH) {
        if (j < WH) return (bi & bj) != 0u;
        if (j >= WH + 4 * NOBJ) return true;
        int cI = j - WH;
        if ((unsigned)(cI - NOBJ) < (unsigned)(2 * NOBJ)) return true;
        int om = (cI < NOBJ) ? cI : cI - 3 * NOBJ;
        return ((bi >> om) & 1u) != 0u;
    }
    if (j >= WH) return true;
    if (i >= WH + 4 * NOBJ) return true;
    int rI = i - WH;
    if ((unsigned)(rI - NOBJ) < (unsigned)(2 * NOBJ)) return true;
    int om = (rI < NOBJ) ? rI : rI - 3 * NOBJ;
    return ((bj >> om) & 1u) != 0u;
}

// ------------- fused attention: 128-key tiles, split staging ---------------
__global__ __launch_bounds__(256, 3) void k_attn(const ushort* __restrict__ Qb,
                                                 const ushort* __restrict__ Kb,
                                                 const ushort* __restrict__ Vt,
                                                 const unsigned* __restrict__ bits,
                                                 ushort* __restrict__ AOb) {
    __shared__ __align__(16) char KtB[128 * 128];     // 16 KB [key][64 d]
    __shared__ __align__(16) char VtB[48 * 256];      // 12 KB [d][128 k]
    __shared__ __align__(16) char PsB[4 * 16 * 256];  // 16 KB per-wave [q][128 k]
    __shared__ __align__(16) unsigned bJB[128];

    const int tid = threadIdx.x;
    const int lane = tid & 63, wv = tid >> 6;
    const int g = lane >> 4, c16 = lane & 15;
    const int l7x = c16 & 7;
    const int rsub = lane >> 3, slotx = lane & 7;

    // XCD-chunked bijective swizzle: 1088 = 8 * 136
    const int bid = blockIdx.x;
    const int logical = (bid & 7) * 136 + (bid >> 3);
    const int bh = logical / NQT, qt = logical - bh * NQT;
    const int b = bh >> 3;
    const int qb_blk = qt * 64;
    const int q0w = qb_blk + wv * 16;
    const int iq = q0w + c16;
    const bool vis_i = (qb_blk + 64 <= WH);

    short8 qf0, qf1;
    {
        const ushort* qp = Qb + ((size_t)bh * NPAD + iq) * 64 + g * 8;
        qf0 = *(const short8*)(qp);
        qf1 = *(const short8*)(qp + 32);
    }
    const unsigned bitsI = bits[(size_t)b * NPAD + iq];

    // ---- strength-reduced staging sources ----
    const ushort* kp = Kb + ((size_t)bh * NPAD + wv * 32 + rsub) * 64 + (slotx ^ rsub) * 8;
    const ushort* vbase = Vt + (size_t)bh * 48 * NPAD;
    int voff[4];
    {
        int st = lane & 15, r4 = lane >> 4;
        #pragma unroll
        for (int u = 0; u < 4; ++u) {
            int d = wv * 16 + u * 4 + r4;          // valid when wv < 3
            voff[u] = d * NPAD + (st ^ (d & 7)) * 8;
        }
    }
    const unsigned* bp = bits + (size_t)b * NPAD + lane;

    auto STAGE_K = [&](const ushort* kpt) {
        #pragma unroll
        for (int u = 0; u < 4; ++u)
            GLD16(KtB + (wv * 32 + u * 8) * 128, kpt + u * 512);
    };
    auto STAGE_V = [&](int vj) {
        if (wv < 3) {
            #pragma unroll
            for (int u = 0; u < 4; ++u)
                GLD16(VtB + (wv * 16 + u * 4) * 256, vbase + vj + voff[u]);
        }
    };
    auto STAGE_B = [&](const unsigned* bpt) {
        if (wv == 3) { GLD4(bJB, bpt); GLD4(bJB + 64, bpt + 64); }
    };

    const int sl0 = (g ^ l7x) * 16;
    const int sl1 = ((4 + g) ^ l7x) * 16;
    const int psw = wv * 4096 + c16 * 256;
    const int swz = l7x << 4;

    float m_run = NEGF, l_run = 0.f;
    f32x4 o0 = {0.f, 0.f, 0.f, 0.f}, o1 = o0, o2 = o0;

    STAGE_K(kp); STAGE_V(0); STAGE_B(bp);
    __syncthreads();

    for (int t = 0; t < NT128; ++t) {
        const int j0 = t * 128;

        // ---- S^T = K . Q^T : 16 MFMA over 128 keys ----
        f32x4 s4[8];
        #pragma unroll
        for (int e8 = 0; e8 < 8; ++e8) {
            const char* arow = KtB + (e8 * 16 + c16) * 128;
            f32x4 a = {0.f, 0.f, 0.f, 0.f};
            a = __builtin_amdgcn_mfma_f32_16x16x32_bf16(*(const short8*)(arow + sl0), qf0, a, 0, 0, 0);
            a = __builtin_amdgcn_mfma_f32_16x16x32_bf16(*(const short8*)(arow + sl1), qf1, a, 0, 0, 0);
            s4[e8] = a;
        }

        // ---- mask (in place) + local pmax ----
        float pmax = NEGF;
        const bool vis_j = (j0 + 128 <= WH);
        const bool diag = ((qt >> 1) == t);
        if (vis_i && vis_j && !diag) {
            #pragma unroll
            for (int e8 = 0; e8 < 8; ++e8) {
                uintx4 bk = *(const uintx4*)&bJB[e8 * 16 + g * 4];
                #pragma unroll
                for (int r = 0; r < 4; ++r) {
                    float x = ((bitsI & bk[r]) != 0u) ? s4[e8][r] : NEGF;
                    s4[e8][r] = x;
                    pmax = fmaxf(pmax, x);
                }
            }
        } else if (vis_i && vis_j) {
            #pragma unroll
            for (int e8 = 0; e8 < 8; ++e8) {
                uintx4 bk = *(const uintx4*)&bJB[e8 * 16 + g * 4];
                #pragma unroll
                for (int r = 0; r < 4; ++r) {
                    int j = j0 + e8 * 16 + g * 4 + r;
                    bool ok = ((bitsI & bk[r]) != 0u) || (iq == j);
                    float x = ok ? s4[e8][r] : NEGF;
                    s4[e8][r] = x;
                    pmax = fmaxf(pmax, x);
                }
            }
        } else {
            #pragma unroll
            for (int e8 = 0; e8 < 8; ++e8) {
                uintx4 bk = *(const uintx4*)&bJB[e8 * 16 + g * 4];
                #pragma unroll
                for (int r = 0; r < 4; ++r) {
                    int j = j0 + e8 * 16 + g * 4 + r;
                    float x = mask_ok(iq, j, bitsI, bk[r]) ? s4[e8][r] : NEGF;
                    s4[e8][r] = x;
                    pmax = fmaxf(pmax, x);
                }
            }
        }

        // ---- online softmax with defer-max ----
        pmax = fmaxf(pmax, __shfl_xor(pmax, 16));
        pmax = fmaxf(pmax, __shfl_xor(pmax, 32));
        bool defer = (pmax <= m_run + 8.f) && (m_run > -1.0e37f);
        if (!__all(defer)) {
            float mnew = fmaxf(m_run, pmax);
            float rs = __builtin_amdgcn_exp2f(m_run - mnew);
            m_run = mnew;
            l_run *= rs;
            float rr0 = __shfl(rs, g * 4 + 0);
            float rr1 = __shfl(rs, g * 4 + 1);
            float rr2 = __shfl(rs, g * 4 + 2);
            float rr3 = __shfl(rs, g * 4 + 3);
            o0[0] *= rr0; o0[1] *= rr1; o0[2] *= rr2; o0[3] *= rr3;
            o1[0] *= rr0; o1[1] *= rr1; o1[2] *= rr2; o1[3] *= rr3;
            o2[0] *= rr0; o2[1] *= rr1; o2[2] *= rr2; o2[3] *= rr3;
        }

        // ---- P = exp2(S - m), packed bf16 -> per-wave LDS ----
        float psum = 0.f;
        #pragma unroll
        for (int e8 = 0; e8 < 8; ++e8) {
            float p0 = __builtin_amdgcn_exp2f(s4[e8][0] - m_run);
            float p1 = __builtin_amdgcn_exp2f(s4[e8][1] - m_run);
            float p2 = __builtin_amdgcn_exp2f(s4[e8][2] - m_run);
            float p3 = __builtin_amdgcn_exp2f(s4[e8][3] - m_run);
            psum += (p0 + p1) + (p2 + p3);
            unsigned w0, w1;
            asm("v_cvt_pk_bf16_f32 %0, %1, %2" : "=v"(w0) : "v"(p0), "v"(p1));
            asm("v_cvt_pk_bf16_f32 %0, %1, %2" : "=v"(w1) : "v"(p2), "v"(p3));
            int s = e8 >> 2, kt = e8 & 3;
            uint2 val; val.x = w0; val.y = w1;
            *(uint2*)(PsB + psw + s * 128 + ((kt * 32 + g * 8) ^ swz)) = val;
        }
        psum += __shfl_xor(psum, 16);
        psum += __shfl_xor(psum, 32);
        l_run += psum;

        __syncthreads();                       // A: all waves done reading K
        kp += 128 * 64; bp += 128;
        if (t + 1 < NT128) { STAGE_K(kp); STAGE_B(bp); }

        // ---- PV: O += P . V, 12 MFMA ----
        #pragma unroll
        for (int s = 0; s < 2; ++s) {
            const char* prow = PsB + psw + s * 128;
            short8 pa0 = *(const short8*)(prow + sl0);
            short8 pa1 = *(const short8*)(prow + sl1);
            const char* v0r = VtB + (0 * 16 + c16) * 256 + s * 128;
            const char* v1r = VtB + (1 * 16 + c16) * 256 + s * 128;
            const char* v2r = VtB + (2 * 16 + c16) * 256 + s * 128;
            o0 = __builtin_amdgcn_mfma_f32_16x16x32_bf16(pa0, *(const short8*)(v0r + sl0), o0, 0, 0, 0);
            o0 = __builtin_amdgcn_mfma_f32_16x16x32_bf16(pa1, *(const short8*)(v0r + sl1), o0, 0, 0, 0);
            o1 = __builtin_amdgcn_mfma_f32_16x16x32_bf16(pa0, *(const short8*)(v1r + sl0), o1, 0, 0, 0);
            o1 = __builtin_amdgcn_mfma_f32_16x16x32_bf16(pa1, *(const short8*)(v1r + sl1), o1, 0, 0, 0);
            o2 = __builtin_amdgcn_mfma_f32_16x16x32_bf16(pa0, *(const short8*)(v2r + sl0), o2, 0, 0, 0);
            o2 = __builtin_amdgcn_mfma_f32_16x16x32_bf16(pa1, *(const short8*)(v2r + sl1), o2, 0, 0, 0);
        }

        __syncthreads();                       // B: all waves done reading V
        if (t + 1 < NT128) STAGE_V((t + 1) * 128);
    }

    // ---- epilogue: /l, bf16 store ----
    float lr0 = __shfl(l_run, g * 4 + 0);
    float lr1 = __shfl(l_run, g * 4 + 1);
    float lr2 = __shfl(l_run, g * 4 + 2);
    float lr3 = __shfl(l_run, g * 4 + 3);
    float inv[4] = {1.f / lr0, 1.f / lr1, 1.f / lr2, 1.f / lr3};
    const int h = bh & 7;
    #pragma unroll
    for (int r = 0; r < 4; ++r) {
        int qrow = q0w + g * 4 + r;
        if (qrow >= N_TOK) continue;
        ushort* dst = AOb + (size_t)(b * N_TOK + qrow) * QDIM + h * DHEAD;
        dst[c16]      = f2bf(o0[r] * inv[r]);
        dst[16 + c16] = f2bf(o1[r] * inv[r]);
        if (c16 < 8) dst[32 + c16] = f2bf(o2[r] * inv[r]);
    }
}

// --------------------------------- launcher ---------------------------------
extern "C" void kernel_launch(void* const* d_in, const int* in_sizes, int n_in,
                              void* d_out, int out_size, void* d_ws, size_t ws_size,
                              hipStream_t stream) {
    const float* x   = (const float*)d_in[0];
    const float* att = (const float*)d_in[1];
    const float* Wq  = (const float*)d_in[2];
    const float* Wk  = (const float*)d_in[3];
    const float* Wv  = (const float*)d_in[4];
    const float* Wo  = (const float*)d_in[5];
    const float* bo  = (const float*)d_in[6];
    float* out = (float*)d_out;

    char* w = (char*)d_ws;
    unsigned* bits = (unsigned*)w;                      // BB*NPAD*4 < 64 KB
    size_t off = 65536;
    ushort* xb    = (ushort*)(w + off); off += (size_t)MPAD * QDIM * 2;
    ushort* WtAll = (ushort*)(w + off); off += (size_t)1280 * QDIM * 2;
    ushort* Qb    = (ushort*)(w + off); off += (size_t)16 * NPAD * 64 * 2;
    ushort* Kb    = (ushort*)(w + off); off += (size_t)16 * NPAD * 64 * 2;
    ushort* Vt    = (ushort*)(w + off); off += (size_t)16 * 48 * NPAD * 2;
    ushort* AOb   = (ushort*)(w + off);

    k_zero<<<1024, 256, 0, stream>>>((u64x2*)Qb, (int)((size_t)16 * NPAD * 64 * 2 / 16));
    k_bits<<<(BB * NPAD + 255) / 256, 256, 0, stream>>>(att, bits);
    k_xcvt<<<(M_ROWS * QDIM / 8 + 255) / 256, 256, 0, stream>>>(x, xb);
    k_wcvt<<<dim3(10, 40), 256, 0, stream>>>(Wq, Wk, Wv, Wo, WtAll);

    k_mm<0><<<dim3(MPAD / 64, 15), 256, 0, stream>>>(xb, WtAll, nullptr, Qb, Kb, Vt, nullptr);
    k_attn<<<16 * NQT, 256, 0, stream>>>(Qb, Kb, Vt, bits, AOb);
    k_mm<1><<<dim3(MPAD / 64, 5), 256, 0, stream>>>(AOb, WtAll + 960 * QDIM, bo,
                                                    nullptr, nullptr, nullptr, out);
}